// Round 9
// baseline (523.109 us; speedup 1.0000x reference)
//
#include <hip/hip_runtime.h>

// Problem constants (match reference setup_inputs)
#define NB 128
#define NL 512
#define NN 1023
#define NT 511
#define ND 256
#define NC 511
#define EPSF 1e-6f

// Source encoding:
//   SRC_ZERO          -> zero vector
//   0..511            -> leaf row r (leafbuf)
//   SLOTC + t         -> output slot of type-2 step t (outbuf)
//   STEPC + t         -> unresolved reference to writer step t (resolution only)
#define SRC_ZERO (-1)
#define SLOTC 4096
#define STEPC 8192

typedef __attribute__((ext_vector_type(8))) short short8;   // 8 x bf16
typedef __attribute__((ext_vector_type(4))) float f32x4;    // MFMA accumulator
typedef __attribute__((ext_vector_type(2))) float f32x2;    // packed fp32 pair

__device__ __forceinline__ unsigned short f2bf(float f) {
  unsigned u = __builtin_bit_cast(unsigned, f);
  u += 0x7FFFu + ((u >> 16) & 1u);   // round-to-nearest-even
  return (unsigned short)(u >> 16);
}

// ---------------------------------------------------------------------------
// Phase 1: embed (normalize emb rows -> leafbuf fp32 + vecb bf16) and cvt_w,
// merged into one launch. blocks [0,16384): embed (4 rows/block);
// blocks [16384,16448): lin_weight -> bf16 padded to 512 rows.  (proven)
// ---------------------------------------------------------------------------
__global__ void __launch_bounds__(256) embed_scatter(
    const int* __restrict__ lcid, const int* __restrict__ cmask,
    const float* __restrict__ emb, const float* __restrict__ lw,
    float* __restrict__ leafbuf, unsigned short* __restrict__ vecb,
    unsigned short* __restrict__ wb) {
  if (blockIdx.x >= 16384) {          // ---- cvt_w ----
    int i   = (blockIdx.x - 16384) * 256 + threadIdx.x;   // [0,16384)
    int row = i >> 5;
    uint4 r = {0u, 0u, 0u, 0u};
    if (row < NC) {
      const float4* v4 = (const float4*)lw;
      float4 x = v4[2 * i], y = v4[2 * i + 1];
      r.x = (unsigned)f2bf(x.x) | ((unsigned)f2bf(x.y) << 16);
      r.y = (unsigned)f2bf(x.z) | ((unsigned)f2bf(x.w) << 16);
      r.z = (unsigned)f2bf(y.x) | ((unsigned)f2bf(y.y) << 16);
      r.w = (unsigned)f2bf(y.z) | ((unsigned)f2bf(y.w) << 16);
    }
    ((uint4*)wb)[i] = r;
    return;
  }
  int rid  = blockIdx.x * 4 + (threadIdx.x >> 6);   // b*NL + l
  int lane = threadIdx.x & 63;
  int slot = lcid[2 * rid];
  int vid  = lcid[2 * rid + 1];
  int msk  = cmask[rid];
  int b    = rid >> 9;                               // / NL
  float4 v = {0.f, 0.f, 0.f, 0.f};
  if (msk) v = ((const float4*)(emb + (size_t)vid * ND))[lane];
  float ss = v.x * v.x + v.y * v.y + v.z * v.z + v.w * v.w;
#pragma unroll
  for (int off = 32; off > 0; off >>= 1) ss += __shfl_down(ss, off, 64);
  ss = __shfl(ss, 0, 64);
  float inv = 1.0f / (sqrtf(ss) + EPSF);   // msk==0: v=0 -> o=0 (no NaN)
  float4 o;
  o.x = v.x * inv; o.y = v.y * inv; o.z = v.z * inv; o.w = v.w * inv;
  ((float4*)(leafbuf + ((size_t)b * 512 + slot) * ND))[lane] = o;
  uint2 pk;
  pk.x = (unsigned)f2bf(o.x) | ((unsigned)f2bf(o.y) << 16);
  pk.y = (unsigned)f2bf(o.z) | ((unsigned)f2bf(o.w) << 16);
  ((uint2*)(vecb + ((size_t)b * NN + slot) * ND))[lane] = pk;
}

// ---------------------------------------------------------------------------
// Phase 2 (merged launch): blocks [0,128) = compose (round-6/8 passing body)
// WITH FUSED GATHER; blocks [128,1152) = leaf-half GEMM (round-1 body, now
// XCD-grouped). Union shared memory (118 KB) -> one block per CU -> no
// co-residency (round-1 poisoning excluded).
//
// Fused gather (NEW): invert fsrc into per-slot linked lists (invHead/
// invNext, atomicExch). Leaf/zero-sourced final rows are converted+written
// to vecb right after resolution (independent of exec). Slot-sourced rows
// are written at exec store time from the in-register result by walking the
// wave-uniform inverse list — zero extra reads. The separate gather kernel
// and the fsrcG d_out staging are deleted.
// ---------------------------------------------------------------------------
struct ComposeSh {
  int4 sinfo4[NT];
  int ptr_[NT];
  int lsA[NT], rsA[NT];
  int lvl[NT], fsrc[NT];
  int invHead[NT], invNext[NT];
  int schedS[NT], schedL[NT], schedR[NT];
  int offs[512], cnt[512], cnt2[512];
  unsigned char deadF[NT], liveF[NT], lzero[512];
  float a_st[16][256];
  float b_st[16][512];
  float s_st[16][512];
  int changed, smax;
};
struct LeafGemmSh { short As[256 * 64]; short Ws[128 * 64]; };
union FuseSh { ComposeSh c; LeafGemmSh g; };

__global__ void __launch_bounds__(1024) compose_leafgemm(
    const int* __restrict__ info, const int* __restrict__ lcid,
    const int* __restrict__ cmask, const float* __restrict__ leafbuf,
    float* __restrict__ outbuf, unsigned short* __restrict__ vecbW,
    const short* __restrict__ vecbS, const short* __restrict__ wbs,
    const float* __restrict__ bias, float* __restrict__ out) {
  __shared__ FuseSh sh;
  const int tid  = threadIdx.x;
  const int lane = tid & 63;
  const int wav  = tid >> 6;

  if (blockIdx.x < NB) {
    // ================= compose (round-8 passing body + fused gather) ========
    const int b = blockIdx.x;
    int4 (&sinfo4)[NT] = sh.c.sinfo4;
    int (&ptr_)[NT] = sh.c.ptr_;
    int (&lsA)[NT] = sh.c.lsA;  int (&rsA)[NT] = sh.c.rsA;
    int (&lvl)[NT] = sh.c.lvl;  int (&fsrc)[NT] = sh.c.fsrc;
    int (&invHead)[NT] = sh.c.invHead; int (&invNext)[NT] = sh.c.invNext;
    int (&schedS)[NT] = sh.c.schedS; int (&schedL)[NT] = sh.c.schedL;
    int (&schedR)[NT] = sh.c.schedR;
    int (&offs)[512] = sh.c.offs; int (&cnt)[512] = sh.c.cnt;
    int (&cnt2)[512] = sh.c.cnt2;
    unsigned char (&deadF)[NT] = sh.c.deadF;
    unsigned char (&liveF)[NT] = sh.c.liveF;
    unsigned char (&lzero)[512] = sh.c.lzero;
    float (&a_st)[16][256] = sh.c.a_st;
    float (&b_st)[16][512] = sh.c.b_st;
    float (&s_st)[16][512] = sh.c.s_st;
    int &changed = sh.c.changed; int &smax = sh.c.smax;

    const float* lb = leafbuf + (size_t)b * 512 * ND;
    float*       ob = outbuf + (size_t)b * NT * ND;
    unsigned short* vb = vecbW + ((size_t)b * NN + 512) * ND;   // final rows

    // ---- load step info + leaf-zero mask ----
    const int4* ib4 = (const int4*)(info + (size_t)b * NT * 4);
    for (int i = tid; i < NT; i += 1024) sinfo4[i] = ib4[i];
    if (tid < 512) lzero[tid] = 1;
    if (tid == 0) smax = 0;
    __syncthreads();
    if (tid < NL) {
      int row = lcid[((size_t)b * NL + tid) * 2];   // slots unique per batch
      lzero[row] = (cmask[(size_t)b * NL + tid] == 0) ? 1 : 0;
    }
    __syncthreads();

    // ---- last-writer scan (broadcast reads; one thread per step) ----
    const int t = tid;
    int4 m1 = {0, 0, 0, 0};
    if (t < NT) m1 = sinfo4[t];
    int l1 = -1, r1 = -1, f1 = -1;
    const int prow = 512 + t;
    for (int tp = 0; tp < NT; ++tp) {
      int4 wi = sinfo4[tp];
      if (wi.x > 0) {   // type-1/2 write row wi.y (in [512,1023))
        if (t < NT && tp < t) { if (wi.y == m1.z) l1 = tp; if (wi.y == m1.w) r1 = tp; }
        if (wi.y == prow) f1 = tp;
      }
    }
    __syncthreads();

    // ---- type-1 chain collapse via pointer jumping ----
    if (t < NT) {
      int v;
      if (m1.x == 2) v = SLOTC + t;
      else if (m1.x == 1) {
        if (m1.z < 512) v = m1.z;
        else v = (l1 >= 0) ? (STEPC + l1) : SRC_ZERO;
      } else v = SRC_ZERO;
      ptr_[t] = v;
    }
    __syncthreads();
    for (int it = 0; it < 10; ++it) {   // 2^10 covers any chain length <= 511
      int v = 0;
      if (t < NT) { v = ptr_[t]; if (v >= STEPC) v = ptr_[v - STEPC]; }
      __syncthreads();
      if (t < NT) ptr_[t] = v;
      __syncthreads();
    }

    // ---- resolve type-2 operands + final row sources ----
    auto normv = [&](int v) -> int {   // masked-out leaf row == zero vector
      if (v >= 0 && v < 512 && lzero[v]) return SRC_ZERO;
      return v;
    };
    auto collapseW = [&](int wstep) -> int {
      int v = (sinfo4[wstep].x == 2) ? (SLOTC + wstep) : ptr_[wstep];
      return normv(v);
    };
    if (t < NT) {
      if (m1.x == 2) {
        int a = (m1.z < 512) ? normv(m1.z) : ((l1 >= 0) ? collapseW(l1) : SRC_ZERO);
        int c = (m1.w < 512) ? normv(m1.w) : ((r1 >= 0) ? collapseW(r1) : SRC_ZERO);
        lsA[t] = a; rsA[t] = c;
        deadF[t] = (a == SRC_ZERO || c == SRC_ZERO) ? 1 : 0;
      } else {
        deadF[t] = 0;
      }
      liveF[t] = 0;
      fsrc[t] = (f1 >= 0) ? collapseW(f1) : SRC_ZERO;
    }
    __syncthreads();

    // ---- zero propagation fixpoint ----
    for (int rounds = 0; rounds < NT; ++rounds) {
      if (tid == 0) changed = 0;
      __syncthreads();
      if (t < NT && m1.x == 2 && !deadF[t]) {
        int a = lsA[t], c = rsA[t];
        if (a >= SLOTC && deadF[a - SLOTC]) { a = SRC_ZERO; lsA[t] = a; }
        if (c >= SLOTC && deadF[c - SLOTC]) { c = SRC_ZERO; rsA[t] = c; }
        if (a == SRC_ZERO || c == SRC_ZERO) { deadF[t] = 1; changed = 1; }
      }
      __syncthreads();
      if (!changed) break;
      __syncthreads();
    }

    // ---- backward liveness (fsrc finalized in its init step) ----
    if (t < NT) {
      int f = fsrc[t];
      if (f >= SLOTC && deadF[f - SLOTC]) { f = SRC_ZERO; fsrc[t] = f; }
      if (f >= SLOTC) liveF[f - SLOTC] = 1;
    }
    __syncthreads();
    for (int rounds = 0; rounds < NT; ++rounds) {
      if (tid == 0) changed = 0;
      __syncthreads();
      if (t < NT && m1.x == 2 && liveF[t] && !deadF[t]) {
        int a = lsA[t], c = rsA[t];
        if (a >= SLOTC && !liveF[a - SLOTC]) { liveF[a - SLOTC] = 1; changed = 1; }
        if (c >= SLOTC && !liveF[c - SLOTC]) { liveF[c - SLOTC] = 1; changed = 1; }
      }
      __syncthreads();
      if (!changed) break;
      __syncthreads();
    }

    // ---- fused gather part 1: inverse lists + leaf/zero final rows ----
    if (t < NT) invHead[t] = -1;
    __syncthreads();
    if (t < NT && fsrc[t] >= SLOTC)
      invNext[t] = atomicExch(&invHead[fsrc[t] - SLOTC], t);
    // leaf/zero-sourced final rows: independent of exec, write now (L2-warm)
    for (int i = wav; i < NT; i += 16) {
      int s = fsrc[i];                 // wave-uniform broadcast read
      if (s < SLOTC) {
        float4 v = {0.f, 0.f, 0.f, 0.f};
        if (s >= 0) v = ((const float4*)(lb + (size_t)s * ND))[lane];
        uint2 pk;
        pk.x = (unsigned)f2bf(v.x) | ((unsigned)f2bf(v.y) << 16);
        pk.y = (unsigned)f2bf(v.z) | ((unsigned)f2bf(v.w) << 16);
        ((uint2*)(vb + (size_t)i * ND))[lane] = pk;
      }
    }
    __syncthreads();                   // invHead/invNext visible for exec

    const bool isLive = (t < NT && m1.x == 2 && liveF[t] && !deadF[t]);

    // ---- ASAP levels via monotone fixpoint ----
    if (t < NT) lvl[t] = 0;
    __syncthreads();
    for (int rounds = 0; rounds < NT; ++rounds) {
      if (tid == 0) changed = 0;
      __syncthreads();
      if (isLive) {
        int nl = 1, a = lsA[t], c = rsA[t];
        if (a >= SLOTC) { int dl = lvl[a - SLOTC] + 1; if (dl > nl) nl = dl; }
        if (c >= SLOTC) { int dl = lvl[c - SLOTC] + 1; if (dl > nl) nl = dl; }
        if (nl > lvl[t]) { lvl[t] = nl; changed = 1; }
      }
      __syncthreads();
      if (!changed) break;
      __syncthreads();
    }
    if (isLive) atomicMax(&smax, lvl[t]);

    // ---- bucket ops by level ----
    if (tid < 512) { cnt[tid] = 0; cnt2[tid] = 0; }
    __syncthreads();
    if (isLive) atomicAdd(&cnt[lvl[t]], 1);
    __syncthreads();
    if (tid < 512) offs[tid] = cnt[tid];
    __syncthreads();
    for (int k = 1; k < 512; k <<= 1) {   // inclusive prefix over levels
      int v = 0;
      if (tid < 512) { v = offs[tid]; if (tid >= k) v += offs[tid - k]; }
      __syncthreads();
      if (tid < 512) offs[tid] = v;
      __syncthreads();
    }
    if (isLive) {
      int d = lvl[t];
      int pos = offs[d - 1] + atomicAdd(&cnt2[d], 1);   // d>=1 always
      schedS[pos] = t; schedL[pos] = lsA[t]; schedR[pos] = rsA[t];
    }
    __syncthreads();

    // ---- level-parallel execution: one op per wave, packed inner loop ----
    const int maxd = smax;
    for (int d = 1; d <= maxd; ++d) {
      const int base = offs[d - 1];
      const int nops = cnt[d];
      const int nch  = (nops + 15) >> 4;
      for (int ch = 0; ch < nch; ++ch) {
        int rel = ch * 16 + wav;
        if (rel < nops) {           // wave-uniform predicate
          int my = base + rel;
          int tt = schedS[my], ls = schedL[my], rs = schedR[my];
          const float* pa = (ls < 512) ? lb + (size_t)ls * ND
                                       : ob + (size_t)(ls - SLOTC) * ND;
          const float* pb = (rs < 512) ? lb + (size_t)rs * ND
                                       : ob + (size_t)(rs - SLOTC) * ND;
          float4 av = ((const float4*)pa)[lane];
          float4 bv = ((const float4*)pb)[lane];
          float nx = __shfl(bv.x, (lane + 1) & 63, 64);
          float4 sv = {bv.y, bv.z, bv.w, nx};
          ((float4*)a_st[wav])[lane]      = av;
          ((float4*)b_st[wav])[lane]      = bv;
          ((float4*)b_st[wav])[lane + 64] = bv;   // doubled for mod-256 window
          ((float4*)s_st[wav])[lane]      = sv;
          ((float4*)s_st[wav])[lane + 64] = sv;
          const float4* a4 = (const float4*)a_st[wav];
          const float4* b4 = (const float4*)b_st[wav];
          const float4* s4 = (const float4*)s_st[wav];
          f32x2 q0 = {0.f, 0.f}, q1 = {0.f, 0.f}, q2 = {0.f, 0.f}, q3 = {0.f, 0.f};
          float4 B0 = b4[lane];
          float4 S0 = s4[lane];
#pragma unroll 8
          for (int i = 0; i < 64; ++i) {
            float4 A  = a4[i];             // uniform -> LDS broadcast
            float4 B1 = b4[lane + i + 1];  // rolling windows, conflict-free
            float4 S1 = s4[lane + i + 1];
            f32x2 Axy = {A.x, A.y},  Azw = {A.z, A.w};
            f32x2 Bxy = {B0.x, B0.y}, Bzw = {B0.z, B0.w};
            f32x2 Sxy = {S0.x, S0.y}, Szw = {S0.z, S0.w};
            f32x2 B1xy = {B1.x, B1.y}, S1xy = {S1.x, S1.y};
            q0 += Axy * Bxy;  q0 += Azw * Bzw;
            q1 += Axy * Sxy;  q1 += Azw * Szw;
            q2 += Axy * Bzw;  q2 += Azw * B1xy;
            q3 += Axy * Szw;  q3 += Azw * S1xy;
            B0 = B1; S0 = S1;
          }
          float c0 = q0.x + q0.y, c1 = q1.x + q1.y;
          float c2 = q2.x + q2.y, c3 = q3.x + q3.y;
          float ss = c0 * c0 + c1 * c1 + c2 * c2 + c3 * c3;
#pragma unroll
          for (int off = 32; off > 0; off >>= 1) ss += __shfl_down(ss, off, 64);
          ss = __shfl(ss, 0, 64);
          float inv = 1.f / (sqrtf(ss) + EPSF);
          float4 res;
          res.x = c0 * inv; res.y = c1 * inv; res.z = c2 * inv; res.w = c3 * inv;
          ((float4*)(ob + (size_t)tt * ND))[lane] = res;
          // fused gather part 2: final rows sourced from this slot —
          // convert the in-register result, walk the wave-uniform list
          int idx = invHead[tt];
          if (idx >= 0) {
            uint2 pk;
            pk.x = (unsigned)f2bf(res.x) | ((unsigned)f2bf(res.y) << 16);
            pk.y = (unsigned)f2bf(res.z) | ((unsigned)f2bf(res.w) << 16);
            do {
              ((uint2*)(vb + (size_t)idx * ND))[lane] = pk;
              idx = invNext[idx];
            } while (idx >= 0);
          }
        }
        // no intra-level barrier: staging wave-private, deps cross-level
      }
      __syncthreads();   // level boundary
    }
    return;
  }

  // ============== leaf-half GEMM (round-1 body, XCD-grouped) ===============
  // 256x128 tile, 16 waves (8x2), rows n<512 only. Hidden under compose.
  // Remap: gidx -> q=gidx>>5, u=gidx&31, pair=q*8+(u&7), ct=u>>3. The 4
  // col-siblings of an A-tile share gidx%8 == blockIdx%8 -> same XCD -> A
  // from L2 (saves ~100 MB hidden HBM traffic; less BW contention).
  const int gidx = blockIdx.x - NB;
  const int pair = (gidx >> 5) * 8 + (gidx & 7);   // [0,256) = b*2+mt
  const int ct   = (gidx >> 3) & 3;                // col-tile [0,4)
  const int b  = pair >> 1;
  const int mt = pair & 1;
  const short* A = vecbS + ((size_t)b * NN + mt * 256) * ND;
  const int c0   = ct * 128;
  const int wr   = wav >> 1;          // 0..7 : 32-row strip
  const int wc   = wav & 1;           // 0..1 : 64-col strip
  const int frow = lane & 15;
  const int quad = lane >> 4;
  f32x4 acc[2][4];
#pragma unroll
  for (int i = 0; i < 2; ++i)
#pragma unroll
    for (int j = 0; j < 4; ++j) acc[i][j] = (f32x4){0.f, 0.f, 0.f, 0.f};

  for (int k0 = 0; k0 < ND; k0 += 64) {
#pragma unroll
    for (int i = 0; i < 2; ++i) {
      int idx = i * 1024 + tid;
      int row = idx >> 3;
      int chn = idx & 7;
      const short* ga = A + (size_t)row * ND + k0 + chn * 8;
      __builtin_amdgcn_global_load_lds(
          (const __attribute__((address_space(1))) void*)ga,
          (__attribute__((address_space(3))) void*)(sh.g.As + idx * 8), 16, 0, 0);
    }
    {
      int row = tid >> 3;
      int chn = tid & 7;
      const short* gw = wbs + (size_t)(c0 + row) * ND + k0 + chn * 8;
      __builtin_amdgcn_global_load_lds(
          (const __attribute__((address_space(1))) void*)gw,
          (__attribute__((address_space(3))) void*)(sh.g.Ws + tid * 8), 16, 0, 0);
    }
    __syncthreads();
#pragma unroll
    for (int ks = 0; ks < 2; ++ks) {
      short8 af[2], wf[4];
#pragma unroll
      for (int mi = 0; mi < 2; ++mi)
        af[mi] = *(const short8*)(sh.g.As + (wr * 32 + mi * 16 + frow) * 64 + ks * 32 + quad * 8);
#pragma unroll
      for (int ci = 0; ci < 4; ++ci)
        wf[ci] = *(const short8*)(sh.g.Ws + (wc * 64 + ci * 16 + frow) * 64 + ks * 32 + quad * 8);
#pragma unroll
      for (int mi = 0; mi < 2; ++mi)
#pragma unroll
        for (int ci = 0; ci < 4; ++ci)
          acc[mi][ci] = __builtin_amdgcn_mfma_f32_16x16x32_bf16(
              af[mi], wf[ci], acc[mi][ci], 0, 0, 0);
    }
    __syncthreads();
  }
#pragma unroll
  for (int mi = 0; mi < 2; ++mi) {
#pragma unroll
    for (int ci = 0; ci < 4; ++ci) {
      int col = c0 + wc * 64 + ci * 16 + frow;
      if (col < NC) {
        float bv = bias[col];
#pragma unroll
        for (int r = 0; r < 4; ++r) {
          int n = mt * 256 + wr * 32 + mi * 16 + quad * 4 + r;   // < 512
          out[((size_t)b * NN + n) * NC + col] = acc[mi][ci][r] + bv;
        }
      }
    }
  }
}

// ---------------------------------------------------------------------------
// Phase 3: internal-row GEMM (n in [512,1023)) — proven swizzled gemm with
// per-batch internal row mapping. Flat grid 2048, XCD-grouped. mt=3 tile has
// 127 rows: store guard n<NN; benign in-bounds A-row overrun.
// ---------------------------------------------------------------------------
union GemmSh {
  struct { short As[128 * 64]; short Ws[128 * 64]; } s;   // 32 KB
  float epi[4][16][65];                                   // 16.6 KB (padded)
};

__global__ void __launch_bounds__(256) gemm_int(
    const short* __restrict__ A, const short* __restrict__ W,
    const float* __restrict__ bias, float* __restrict__ out) {
  __shared__ GemmSh sh;
  int i = blockIdx.x;                       // [0,2048)
  int mtile = (i >> 5) * 8 + (i & 7);       // [0,512)
  int c     = (i >> 3) & 3;                 // [0,4)
  int b     = mtile >> 2;
  int mt    = mtile & 3;
  size_t arow = (size_t)b * NN + 512 + mt * 128;   // global A-row base
  int tid  = threadIdx.x;
  int lane = tid & 63;
  int w    = tid >> 6;
  int c0   = c * 128;
  int wm   = (w & 1) * 64;
  int wc   = (w >> 1) * 64;
  int frow = lane & 15;
  int quad = lane >> 4;
  f32x4 acc[4][4];
#pragma unroll
  for (int a = 0; a < 4; ++a)
#pragma unroll
    for (int j = 0; j < 4; ++j) acc[a][j] = (f32x4){0.f, 0.f, 0.f, 0.f};

  for (int k0 = 0; k0 < ND; k0 += 64) {
#pragma unroll
    for (int a = 0; a < 4; ++a) {
      int idx = a * 256 + tid;
      int row = idx >> 3;
      int ch  = idx & 7;
      int chs = ch ^ (row & 7);   // pre-swizzled source chunk (rule #21)
      const short* ga = A + (arow + row) * ND + k0 + chs * 8;
      const short* gw = W + (size_t)(c0 + row) * ND + k0 + chs * 8;
      __builtin_amdgcn_global_load_lds(
          (const __attribute__((address_space(1))) void*)ga,
          (__attribute__((address_space(3))) void*)(sh.s.As + idx * 8), 16, 0, 0);
      __builtin_amdgcn_global_load_lds(
          (const __attribute__((address_space(1))) void*)gw,
          (__attribute__((address_space(3))) void*)(sh.s.Ws + idx * 8), 16, 0, 0);
    }
    __syncthreads();
#pragma unroll
    for (int ks = 0; ks < 2; ++ks) {
      short8 af[4], wf[4];
#pragma unroll
      for (int mi = 0; mi < 4; ++mi) {
        int r = wm + mi * 16 + frow;
        int cc = (ks * 4 + quad) ^ (r & 7);
        af[mi] = *(const short8*)(sh.s.As + r * 64 + cc * 8);
      }
#pragma unroll
      for (int ci = 0; ci < 4; ++ci) {
        int r = wc + ci * 16 + frow;
        int cc = (ks * 4 + quad) ^ (r & 7);
        wf[ci] = *(const short8*)(sh.s.Ws + r * 64 + cc * 8);
      }
#pragma unroll
      for (int mi = 0; mi < 4; ++mi)
#pragma unroll
        for (int ci = 0; ci < 4; ++ci)
          acc[mi][ci] = __builtin_amdgcn_mfma_f32_16x16x32_bf16(
              af[mi], wf[ci], acc[mi][ci], 0, 0, 0);
    }
    __syncthreads();
  }

  // ---- coalesced epilogue: per-wave 16x64 transpose through LDS ----
  int colg = c0 + wc + lane;                       // this lane's output column
  float bv = (colg < NC) ? bias[colg] : 0.f;
#pragma unroll
  for (int mi = 0; mi < 4; ++mi) {
#pragma unroll
    for (int ci = 0; ci < 4; ++ci)
#pragma unroll
      for (int r = 0; r < 4; ++r)
        sh.epi[w][quad * 4 + r][ci * 16 + frow] = acc[mi][ci][r];
    // same-wave DS in-order: the reads below see the writes above
    if (colg < NC) {
      int nbase = 512 + mt * 128 + wm + mi * 16;
#pragma unroll
      for (int rr = 0; rr < 16; ++rr) {
        int n = nbase + rr;
        if (n < NN)
          out[((size_t)b * NN + n) * NC + colg] = sh.epi[w][rr][lane] + bv;
      }
    }
  }
}

// ---------------------------------------------------------------------------
// Workspace layout (201,392,128 bytes — unchanged):
//   [0)           leafbuf fp32 [B][512][D]  =  67,108,864 B
//   [67108864)    outbuf  fp32 [B][511][D]  =  66,977,792 B
//   [134086656)   vecb    bf16 [B][1023][D] =  67,043,328 B
//   [201129984)   wb      bf16 [512][D]     =     262,144 B
// No d_out staging anymore: gather is fused into compose (inverse lists).
// ---------------------------------------------------------------------------
extern "C" void kernel_launch(void* const* d_in, const int* in_sizes, int n_in,
                              void* d_out, int out_size, void* d_ws, size_t ws_size,
                              hipStream_t stream) {
  const int*   lcid  = (const int*)d_in[1];
  const int*   cmask = (const int*)d_in[2];
  const int*   cinfo = (const int*)d_in[3];
  const float* emb   = (const float*)d_in[4];
  const float* lw    = (const float*)d_in[5];
  const float* lbias = (const float*)d_in[6];
  float*       out   = (float*)d_out;

  char* ws = (char*)d_ws;
  float*          leafbuf = (float*)ws;
  float*          outbuf  = (float*)(ws + 67108864);
  unsigned short* vecb    = (unsigned short*)(ws + 134086656);
  unsigned short* wb      = (unsigned short*)(ws + 201129984);

  embed_scatter<<<16448, 256, 0, stream>>>(lcid, cmask, emb, lw,
                                           leafbuf, vecb, wb);
  compose_leafgemm<<<NB + 1024, 1024, 0, stream>>>(
      cinfo, lcid, cmask, leafbuf, outbuf, vecb,
      (const short*)vecb, (const short*)wb, lbias, out);
  gemm_int<<<2048, 256, 0, stream>>>(
      (const short*)vecb, (const short*)wb, lbias, out);
}

// Round 10
// 480.379 us; speedup vs baseline: 1.0890x; 1.0890x over previous
//
#include <hip/hip_runtime.h>

// Problem constants (match reference setup_inputs)
#define NB 128
#define NL 512
#define NN 1023
#define NT 511
#define ND 256
#define NC 511
#define EPSF 1e-6f

// Source encoding:
//   SRC_ZERO          -> zero vector
//   0..511            -> leaf row r (leafbuf)
//   SLOTC + t         -> output slot of type-2 step t (outbuf)
//   STEPC + t         -> unresolved reference to writer step t (resolution only)
#define SRC_ZERO (-1)
#define SLOTC 4096
#define STEPC 8192

typedef __attribute__((ext_vector_type(8))) short short8;   // 8 x bf16
typedef __attribute__((ext_vector_type(4))) float f32x4;    // MFMA accumulator
typedef __attribute__((ext_vector_type(2))) float f32x2;    // packed fp32 pair

__device__ __forceinline__ unsigned short f2bf(float f) {
  unsigned u = __builtin_bit_cast(unsigned, f);
  u += 0x7FFFu + ((u >> 16) & 1u);   // round-to-nearest-even
  return (unsigned short)(u >> 16);
}

// ---------------------------------------------------------------------------
// Phase 1: embed (normalize emb rows -> leafbuf fp32 + vecb bf16) and cvt_w,
// merged into one launch. blocks [0,16384): embed (4 rows/block);
// blocks [16384,16448): lin_weight -> bf16 padded to 512 rows.  (proven)
// ---------------------------------------------------------------------------
__global__ void __launch_bounds__(256) embed_scatter(
    const int* __restrict__ lcid, const int* __restrict__ cmask,
    const float* __restrict__ emb, const float* __restrict__ lw,
    float* __restrict__ leafbuf, unsigned short* __restrict__ vecb,
    unsigned short* __restrict__ wb) {
  if (blockIdx.x >= 16384) {          // ---- cvt_w ----
    int i   = (blockIdx.x - 16384) * 256 + threadIdx.x;   // [0,16384)
    int row = i >> 5;
    uint4 r = {0u, 0u, 0u, 0u};
    if (row < NC) {
      const float4* v4 = (const float4*)lw;
      float4 x = v4[2 * i], y = v4[2 * i + 1];
      r.x = (unsigned)f2bf(x.x) | ((unsigned)f2bf(x.y) << 16);
      r.y = (unsigned)f2bf(x.z) | ((unsigned)f2bf(x.w) << 16);
      r.z = (unsigned)f2bf(y.x) | ((unsigned)f2bf(y.y) << 16);
      r.w = (unsigned)f2bf(y.z) | ((unsigned)f2bf(y.w) << 16);
    }
    ((uint4*)wb)[i] = r;
    return;
  }
  int rid  = blockIdx.x * 4 + (threadIdx.x >> 6);   // b*NL + l
  int lane = threadIdx.x & 63;
  int slot = lcid[2 * rid];
  int vid  = lcid[2 * rid + 1];
  int msk  = cmask[rid];
  int b    = rid >> 9;                               // / NL
  float4 v = {0.f, 0.f, 0.f, 0.f};
  if (msk) v = ((const float4*)(emb + (size_t)vid * ND))[lane];
  float ss = v.x * v.x + v.y * v.y + v.z * v.z + v.w * v.w;
#pragma unroll
  for (int off = 32; off > 0; off >>= 1) ss += __shfl_down(ss, off, 64);
  ss = __shfl(ss, 0, 64);
  float inv = 1.0f / (sqrtf(ss) + EPSF);   // msk==0: v=0 -> o=0 (no NaN)
  float4 o;
  o.x = v.x * inv; o.y = v.y * inv; o.z = v.z * inv; o.w = v.w * inv;
  ((float4*)(leafbuf + ((size_t)b * 512 + slot) * ND))[lane] = o;
  uint2 pk;
  pk.x = (unsigned)f2bf(o.x) | ((unsigned)f2bf(o.y) << 16);
  pk.y = (unsigned)f2bf(o.z) | ((unsigned)f2bf(o.w) << 16);
  ((uint2*)(vecb + ((size_t)b * NN + slot) * ND))[lane] = pk;
}

// ---------------------------------------------------------------------------
// Phase 2 (merged launch): blocks [0,128) = compose (round-6 PASSING kernel,
// body verbatim via reference-bound names); blocks [128,1152) = leaf-half
// GEMM (round-1 hardware-passed body). Shared memory is a UNION (114 KB) so
// every block allocates 114 KB -> ONE block per CU -> the round-1 poisoning
// mechanism (gemm co-resident on compose CUs, LDS-pipe contention) is
// physically excluded. No data deps between the two halves (leaf-gemm reads
// only embed outputs; compose writes outbuf/fsrcG for later launches).
// ---------------------------------------------------------------------------
struct ComposeSh {
  int4 sinfo4[NT];
  int ptr_[NT];
  int lsA[NT], rsA[NT];
  int lvl[NT], fsrc[NT];
  int schedS[NT], schedL[NT], schedR[NT];
  int offs[512], cnt[512], cnt2[512];
  unsigned char deadF[NT], liveF[NT], lzero[512];
  float a_st[16][256];
  float b_st[16][512];
  float s_st[16][512];
  int changed, smax;
};
struct LeafGemmSh { short As[256 * 64]; short Ws[128 * 64]; };
union FuseSh { ComposeSh c; LeafGemmSh g; };

__global__ void __launch_bounds__(1024) compose_leafgemm(
    const int* __restrict__ info, const int* __restrict__ lcid,
    const int* __restrict__ cmask, const float* __restrict__ leafbuf,
    float* __restrict__ outbuf, int* __restrict__ fsrcG,
    const short* __restrict__ vecbS, const short* __restrict__ wbs,
    const float* __restrict__ bias, float* __restrict__ out) {
  __shared__ FuseSh sh;
  const int tid  = threadIdx.x;
  const int lane = tid & 63;
  const int wav  = tid >> 6;

  if (blockIdx.x < NB) {
    // ================= compose (round-6 passing body, verbatim) =============
    const int b = blockIdx.x;
    int4 (&sinfo4)[NT] = sh.c.sinfo4;
    int (&ptr_)[NT] = sh.c.ptr_;
    int (&lsA)[NT] = sh.c.lsA;  int (&rsA)[NT] = sh.c.rsA;
    int (&lvl)[NT] = sh.c.lvl;  int (&fsrc)[NT] = sh.c.fsrc;
    int (&schedS)[NT] = sh.c.schedS; int (&schedL)[NT] = sh.c.schedL;
    int (&schedR)[NT] = sh.c.schedR;
    int (&offs)[512] = sh.c.offs; int (&cnt)[512] = sh.c.cnt;
    int (&cnt2)[512] = sh.c.cnt2;
    unsigned char (&deadF)[NT] = sh.c.deadF;
    unsigned char (&liveF)[NT] = sh.c.liveF;
    unsigned char (&lzero)[512] = sh.c.lzero;
    float (&a_st)[16][256] = sh.c.a_st;
    float (&b_st)[16][512] = sh.c.b_st;
    float (&s_st)[16][512] = sh.c.s_st;
    int &changed = sh.c.changed; int &smax = sh.c.smax;

    const float* lb = leafbuf + (size_t)b * 512 * ND;
    float*       ob = outbuf + (size_t)b * NT * ND;

    // ---- load step info + leaf-zero mask ----
    const int4* ib4 = (const int4*)(info + (size_t)b * NT * 4);
    for (int i = tid; i < NT; i += 1024) sinfo4[i] = ib4[i];
    if (tid < 512) lzero[tid] = 1;
    if (tid == 0) smax = 0;
    __syncthreads();
    if (tid < NL) {
      int row = lcid[((size_t)b * NL + tid) * 2];   // slots unique per batch
      lzero[row] = (cmask[(size_t)b * NL + tid] == 0) ? 1 : 0;
    }
    __syncthreads();

    // ---- last-writer scan (broadcast reads; one thread per step) ----
    const int t = tid;
    int4 m1 = {0, 0, 0, 0};
    if (t < NT) m1 = sinfo4[t];
    int l1 = -1, r1 = -1, f1 = -1;
    const int prow = 512 + t;
    for (int tp = 0; tp < NT; ++tp) {
      int4 wi = sinfo4[tp];
      if (wi.x > 0) {   // type-1/2 write row wi.y (in [512,1023))
        if (t < NT && tp < t) { if (wi.y == m1.z) l1 = tp; if (wi.y == m1.w) r1 = tp; }
        if (wi.y == prow) f1 = tp;
      }
    }
    __syncthreads();

    // ---- type-1 chain collapse via pointer jumping ----
    if (t < NT) {
      int v;
      if (m1.x == 2) v = SLOTC + t;
      else if (m1.x == 1) {
        if (m1.z < 512) v = m1.z;
        else v = (l1 >= 0) ? (STEPC + l1) : SRC_ZERO;
      } else v = SRC_ZERO;
      ptr_[t] = v;
    }
    __syncthreads();
    for (int it = 0; it < 10; ++it) {   // 2^10 covers any chain length <= 511
      int v = 0;
      if (t < NT) { v = ptr_[t]; if (v >= STEPC) v = ptr_[v - STEPC]; }
      __syncthreads();
      if (t < NT) ptr_[t] = v;
      __syncthreads();
    }

    // ---- resolve type-2 operands + final row sources ----
    auto normv = [&](int v) -> int {   // masked-out leaf row == zero vector
      if (v >= 0 && v < 512 && lzero[v]) return SRC_ZERO;
      return v;
    };
    auto collapseW = [&](int wstep) -> int {
      int v = (sinfo4[wstep].x == 2) ? (SLOTC + wstep) : ptr_[wstep];
      return normv(v);
    };
    if (t < NT) {
      if (m1.x == 2) {
        int a = (m1.z < 512) ? normv(m1.z) : ((l1 >= 0) ? collapseW(l1) : SRC_ZERO);
        int c = (m1.w < 512) ? normv(m1.w) : ((r1 >= 0) ? collapseW(r1) : SRC_ZERO);
        lsA[t] = a; rsA[t] = c;
        deadF[t] = (a == SRC_ZERO || c == SRC_ZERO) ? 1 : 0;
      } else {
        deadF[t] = 0;
      }
      liveF[t] = 0;
      fsrc[t] = (f1 >= 0) ? collapseW(f1) : SRC_ZERO;
    }
    __syncthreads();

    // ---- zero propagation fixpoint ----
    for (int rounds = 0; rounds < NT; ++rounds) {
      if (tid == 0) changed = 0;
      __syncthreads();
      if (t < NT && m1.x == 2 && !deadF[t]) {
        int a = lsA[t], c = rsA[t];
        if (a >= SLOTC && deadF[a - SLOTC]) { a = SRC_ZERO; lsA[t] = a; }
        if (c >= SLOTC && deadF[c - SLOTC]) { c = SRC_ZERO; rsA[t] = c; }
        if (a == SRC_ZERO || c == SRC_ZERO) { deadF[t] = 1; changed = 1; }
      }
      __syncthreads();
      if (!changed) break;
      __syncthreads();
    }

    // ---- backward liveness ----
    if (t < NT) {
      int f = fsrc[t];
      if (f >= SLOTC && deadF[f - SLOTC]) { f = SRC_ZERO; fsrc[t] = f; }
      if (f >= SLOTC) liveF[f - SLOTC] = 1;
    }
    __syncthreads();
    for (int rounds = 0; rounds < NT; ++rounds) {
      if (tid == 0) changed = 0;
      __syncthreads();
      if (t < NT && m1.x == 2 && liveF[t] && !deadF[t]) {
        int a = lsA[t], c = rsA[t];
        if (a >= SLOTC && !liveF[a - SLOTC]) { liveF[a - SLOTC] = 1; changed = 1; }
        if (c >= SLOTC && !liveF[c - SLOTC]) { liveF[c - SLOTC] = 1; changed = 1; }
      }
      __syncthreads();
      if (!changed) break;
      __syncthreads();
    }

    const bool isLive = (t < NT && m1.x == 2 && liveF[t] && !deadF[t]);

    // ---- ASAP levels via monotone fixpoint ----
    if (t < NT) lvl[t] = 0;
    __syncthreads();
    for (int rounds = 0; rounds < NT; ++rounds) {
      if (tid == 0) changed = 0;
      __syncthreads();
      if (isLive) {
        int nl = 1, a = lsA[t], c = rsA[t];
        if (a >= SLOTC) { int dl = lvl[a - SLOTC] + 1; if (dl > nl) nl = dl; }
        if (c >= SLOTC) { int dl = lvl[c - SLOTC] + 1; if (dl > nl) nl = dl; }
        if (nl > lvl[t]) { lvl[t] = nl; changed = 1; }
      }
      __syncthreads();
      if (!changed) break;
      __syncthreads();
    }
    if (isLive) atomicMax(&smax, lvl[t]);

    // ---- bucket ops by level ----
    if (tid < 512) { cnt[tid] = 0; cnt2[tid] = 0; }
    __syncthreads();
    if (isLive) atomicAdd(&cnt[lvl[t]], 1);
    __syncthreads();
    if (tid < 512) offs[tid] = cnt[tid];
    __syncthreads();
    for (int k = 1; k < 512; k <<= 1) {   // inclusive prefix over levels
      int v = 0;
      if (tid < 512) { v = offs[tid]; if (tid >= k) v += offs[tid - k]; }
      __syncthreads();
      if (tid < 512) offs[tid] = v;
      __syncthreads();
    }
    if (isLive) {
      int d = lvl[t];
      int pos = offs[d - 1] + atomicAdd(&cnt2[d], 1);   // d>=1 always
      schedS[pos] = t; schedL[pos] = lsA[t]; schedR[pos] = rsA[t];
    }
    __syncthreads();

    // ---- level-parallel execution: one op per wave, packed inner loop ----
    const int maxd = smax;
    for (int d = 1; d <= maxd; ++d) {
      const int base = offs[d - 1];
      const int nops = cnt[d];
      const int nch  = (nops + 15) >> 4;
      for (int ch = 0; ch < nch; ++ch) {
        int rel = ch * 16 + wav;
        if (rel < nops) {           // wave-uniform predicate
          int my = base + rel;
          int tt = schedS[my], ls = schedL[my], rs = schedR[my];
          const float* pa = (ls < 512) ? lb + (size_t)ls * ND
                                       : ob + (size_t)(ls - SLOTC) * ND;
          const float* pb = (rs < 512) ? lb + (size_t)rs * ND
                                       : ob + (size_t)(rs - SLOTC) * ND;
          float4 av = ((const float4*)pa)[lane];
          float4 bv = ((const float4*)pb)[lane];
          float nx = __shfl(bv.x, (lane + 1) & 63, 64);
          float4 sv = {bv.y, bv.z, bv.w, nx};
          ((float4*)a_st[wav])[lane]      = av;
          ((float4*)b_st[wav])[lane]      = bv;
          ((float4*)b_st[wav])[lane + 64] = bv;   // doubled for mod-256 window
          ((float4*)s_st[wav])[lane]      = sv;
          ((float4*)s_st[wav])[lane + 64] = sv;
          const float4* a4 = (const float4*)a_st[wav];
          const float4* b4 = (const float4*)b_st[wav];
          const float4* s4 = (const float4*)s_st[wav];
          f32x2 q0 = {0.f, 0.f}, q1 = {0.f, 0.f}, q2 = {0.f, 0.f}, q3 = {0.f, 0.f};
          float4 B0 = b4[lane];
          float4 S0 = s4[lane];
#pragma unroll 8
          for (int i = 0; i < 64; ++i) {
            float4 A  = a4[i];             // uniform -> LDS broadcast
            float4 B1 = b4[lane + i + 1];  // rolling windows, conflict-free
            float4 S1 = s4[lane + i + 1];
            f32x2 Axy = {A.x, A.y},  Azw = {A.z, A.w};
            f32x2 Bxy = {B0.x, B0.y}, Bzw = {B0.z, B0.w};
            f32x2 Sxy = {S0.x, S0.y}, Szw = {S0.z, S0.w};
            f32x2 B1xy = {B1.x, B1.y}, S1xy = {S1.x, S1.y};
            q0 += Axy * Bxy;  q0 += Azw * Bzw;
            q1 += Axy * Sxy;  q1 += Azw * Szw;
            q2 += Axy * Bzw;  q2 += Azw * B1xy;
            q3 += Axy * Szw;  q3 += Azw * S1xy;
            B0 = B1; S0 = S1;
          }
          float c0 = q0.x + q0.y, c1 = q1.x + q1.y;
          float c2 = q2.x + q2.y, c3 = q3.x + q3.y;
          float ss = c0 * c0 + c1 * c1 + c2 * c2 + c3 * c3;
#pragma unroll
          for (int off = 32; off > 0; off >>= 1) ss += __shfl_down(ss, off, 64);
          ss = __shfl(ss, 0, 64);
          float inv = 1.f / (sqrtf(ss) + EPSF);
          float4 res;
          res.x = c0 * inv; res.y = c1 * inv; res.z = c2 * inv; res.w = c3 * inv;
          ((float4*)(ob + (size_t)tt * ND))[lane] = res;
        }
        // no intra-level barrier: staging wave-private, deps cross-level
      }
      __syncthreads();   // level boundary
    }

    // ---- export final-row sources for the gather kernel ----
    for (int i = tid; i < NT; i += 1024) fsrcG[b * NT + i] = fsrc[i];
    return;
  }

  // ============== leaf-half GEMM (round-1 hardware-passed body) ============
  // 256x128 tile, 16 waves (8x2), rows n<512 only. Hidden under compose.
  const int gidx = blockIdx.x - NB;
  const int b  = gidx >> 3;
  const int mt = (gidx >> 2) & 1;     // 2 m-tiles of 256 leaf rows
  const int ct = gidx & 3;            // 4 col-tiles of 128
  const short* A = vecbS + ((size_t)b * NN + mt * 256) * ND;
  const int c0   = ct * 128;
  const int wr   = wav >> 1;          // 0..7 : 32-row strip
  const int wc   = wav & 1;           // 0..1 : 64-col strip
  const int frow = lane & 15;
  const int quad = lane >> 4;
  f32x4 acc[2][4];
#pragma unroll
  for (int i = 0; i < 2; ++i)
#pragma unroll
    for (int j = 0; j < 4; ++j) acc[i][j] = (f32x4){0.f, 0.f, 0.f, 0.f};

  for (int k0 = 0; k0 < ND; k0 += 64) {
#pragma unroll
    for (int i = 0; i < 2; ++i) {
      int idx = i * 1024 + tid;
      int row = idx >> 3;
      int chn = idx & 7;
      const short* ga = A + (size_t)row * ND + k0 + chn * 8;
      __builtin_amdgcn_global_load_lds(
          (const __attribute__((address_space(1))) void*)ga,
          (__attribute__((address_space(3))) void*)(sh.g.As + idx * 8), 16, 0, 0);
    }
    {
      int row = tid >> 3;
      int chn = tid & 7;
      const short* gw = wbs + (size_t)(c0 + row) * ND + k0 + chn * 8;
      __builtin_amdgcn_global_load_lds(
          (const __attribute__((address_space(1))) void*)gw,
          (__attribute__((address_space(3))) void*)(sh.g.Ws + tid * 8), 16, 0, 0);
    }
    __syncthreads();
#pragma unroll
    for (int ks = 0; ks < 2; ++ks) {
      short8 af[2], wf[4];
#pragma unroll
      for (int mi = 0; mi < 2; ++mi)
        af[mi] = *(const short8*)(sh.g.As + (wr * 32 + mi * 16 + frow) * 64 + ks * 32 + quad * 8);
#pragma unroll
      for (int ci = 0; ci < 4; ++ci)
        wf[ci] = *(const short8*)(sh.g.Ws + (wc * 64 + ci * 16 + frow) * 64 + ks * 32 + quad * 8);
#pragma unroll
      for (int mi = 0; mi < 2; ++mi)
#pragma unroll
        for (int ci = 0; ci < 4; ++ci)
          acc[mi][ci] = __builtin_amdgcn_mfma_f32_16x16x32_bf16(
              af[mi], wf[ci], acc[mi][ci], 0, 0, 0);
    }
    __syncthreads();
  }
#pragma unroll
  for (int mi = 0; mi < 2; ++mi) {
#pragma unroll
    for (int ci = 0; ci < 4; ++ci) {
      int col = c0 + wc * 64 + ci * 16 + frow;
      if (col < NC) {
        float bv = bias[col];
#pragma unroll
        for (int r = 0; r < 4; ++r) {
          int n = mt * 256 + wr * 32 + mi * 16 + quad * 4 + r;   // < 512
          out[((size_t)b * NN + n) * NC + col] = acc[mi][ci][r] + bv;
        }
      }
    }
  }
}

// ---------------------------------------------------------------------------
// Phase 3: full-grid gather of parent rows -> vecb (bf16). One wave per row.
// (proven; fsrcG lives in out's batch-0 internal-row region)
// ---------------------------------------------------------------------------
__global__ void __launch_bounds__(256) gather_rows(
    const int* __restrict__ fsrcG, const float* __restrict__ leafbuf,
    const float* __restrict__ outbuf, unsigned short* __restrict__ vecb) {
  int rid  = blockIdx.x * 4 + (threadIdx.x >> 6);   // b*NT + idx  (exact grid)
  int lane = threadIdx.x & 63;
  int b    = rid / NT;
  int idx  = rid - b * NT;
  int s    = fsrcG[rid];
  float4 v = {0.f, 0.f, 0.f, 0.f};
  if (s >= 0) {
    const float* src = (s < 512)
        ? (leafbuf + ((size_t)b * 512 + s) * ND)
        : (outbuf + ((size_t)b * NT + (s - SLOTC)) * ND);
    v = ((const float4*)src)[lane];
  }
  uint2 pk;
  pk.x = (unsigned)f2bf(v.x) | ((unsigned)f2bf(v.y) << 16);
  pk.y = (unsigned)f2bf(v.z) | ((unsigned)f2bf(v.w) << 16);
  ((uint2*)(vecb + ((size_t)b * NN + 512 + idx) * ND))[lane] = pk;
}

// ---------------------------------------------------------------------------
// Phase 4: internal-row GEMM (n in [512,1023)) — proven swizzled gemm with
// per-batch internal row mapping. Flat grid 2048, XCD-grouped. mt=3 tile has
// 127 rows: store guard n<NN; benign in-bounds A-row overrun.
// Overwrites the fsrcG staging bytes in d_out (gather already consumed them).
// ---------------------------------------------------------------------------
union GemmSh {
  struct { short As[128 * 64]; short Ws[128 * 64]; } s;   // 32 KB
  float epi[4][16][65];                                   // 16.6 KB (padded)
};

__global__ void __launch_bounds__(256) gemm_int(
    const short* __restrict__ A, const short* __restrict__ W,
    const float* __restrict__ bias, float* __restrict__ out) {
  __shared__ GemmSh sh;
  int i = blockIdx.x;                       // [0,2048)
  int mtile = (i >> 5) * 8 + (i & 7);       // [0,512)
  int c     = (i >> 3) & 3;                 // [0,4)
  int b     = mtile >> 2;
  int mt    = mtile & 3;
  size_t arow = (size_t)b * NN + 512 + mt * 128;   // global A-row base
  int tid  = threadIdx.x;
  int lane = tid & 63;
  int w    = tid >> 6;
  int c0   = c * 128;
  int wm   = (w & 1) * 64;
  int wc   = (w >> 1) * 64;
  int frow = lane & 15;
  int quad = lane >> 4;
  f32x4 acc[4][4];
#pragma unroll
  for (int a = 0; a < 4; ++a)
#pragma unroll
    for (int j = 0; j < 4; ++j) acc[a][j] = (f32x4){0.f, 0.f, 0.f, 0.f};

  for (int k0 = 0; k0 < ND; k0 += 64) {
#pragma unroll
    for (int a = 0; a < 4; ++a) {
      int idx = a * 256 + tid;
      int row = idx >> 3;
      int ch  = idx & 7;
      int chs = ch ^ (row & 7);   // pre-swizzled source chunk (rule #21)
      const short* ga = A + (arow + row) * ND + k0 + chs * 8;
      const short* gw = W + (size_t)(c0 + row) * ND + k0 + chs * 8;
      __builtin_amdgcn_global_load_lds(
          (const __attribute__((address_space(1))) void*)ga,
          (__attribute__((address_space(3))) void*)(sh.s.As + idx * 8), 16, 0, 0);
      __builtin_amdgcn_global_load_lds(
          (const __attribute__((address_space(1))) void*)gw,
          (__attribute__((address_space(3))) void*)(sh.s.Ws + idx * 8), 16, 0, 0);
    }
    __syncthreads();
#pragma unroll
    for (int ks = 0; ks < 2; ++ks) {
      short8 af[4], wf[4];
#pragma unroll
      for (int mi = 0; mi < 4; ++mi) {
        int r = wm + mi * 16 + frow;
        int cc = (ks * 4 + quad) ^ (r & 7);
        af[mi] = *(const short8*)(sh.s.As + r * 64 + cc * 8);
      }
#pragma unroll
      for (int ci = 0; ci < 4; ++ci) {
        int r = wc + ci * 16 + frow;
        int cc = (ks * 4 + quad) ^ (r & 7);
        wf[ci] = *(const short8*)(sh.s.Ws + r * 64 + cc * 8);
      }
#pragma unroll
      for (int mi = 0; mi < 4; ++mi)
#pragma unroll
        for (int ci = 0; ci < 4; ++ci)
          acc[mi][ci] = __builtin_amdgcn_mfma_f32_16x16x32_bf16(
              af[mi], wf[ci], acc[mi][ci], 0, 0, 0);
    }
    __syncthreads();
  }

  // ---- coalesced epilogue: per-wave 16x64 transpose through LDS ----
  int colg = c0 + wc + lane;                       // this lane's output column
  float bv = (colg < NC) ? bias[colg] : 0.f;
#pragma unroll
  for (int mi = 0; mi < 4; ++mi) {
#pragma unroll
    for (int ci = 0; ci < 4; ++ci)
#pragma unroll
      for (int r = 0; r < 4; ++r)
        sh.epi[w][quad * 4 + r][ci * 16 + frow] = acc[mi][ci][r];
    // same-wave DS in-order: the reads below see the writes above
    if (colg < NC) {
      int nbase = 512 + mt * 128 + wm + mi * 16;
#pragma unroll
      for (int rr = 0; rr < 16; ++rr) {
        int n = nbase + rr;
        if (n < NN)
          out[((size_t)b * NN + n) * NC + colg] = sh.epi[w][rr][lane] + bv;
      }
    }
  }
}

// ---------------------------------------------------------------------------
// Workspace layout (201,392,128 bytes — unchanged):
//   [0)           leafbuf fp32 [B][512][D]  =  67,108,864 B
//   [67108864)    outbuf  fp32 [B][511][D]  =  66,977,792 B
//   [134086656)   vecb    bf16 [B][1023][D] =  67,043,328 B
//   [201129984)   wb      bf16 [512][D]     =     262,144 B
// fsrcG (128*511 ints = 261,632 B) staged in d_out's BATCH-0 INTERNAL region
// (float offset 512*NC): leaf-gemm (same launch as compose) writes only
// rows n<512 -> no overlap; gather reads it; gemm_int overwrites it after.
// ---------------------------------------------------------------------------
extern "C" void kernel_launch(void* const* d_in, const int* in_sizes, int n_in,
                              void* d_out, int out_size, void* d_ws, size_t ws_size,
                              hipStream_t stream) {
  const int*   lcid  = (const int*)d_in[1];
  const int*   cmask = (const int*)d_in[2];
  const int*   cinfo = (const int*)d_in[3];
  const float* emb   = (const float*)d_in[4];
  const float* lw    = (const float*)d_in[5];
  const float* lbias = (const float*)d_in[6];
  float*       out   = (float*)d_out;

  char* ws = (char*)d_ws;
  float*          leafbuf = (float*)ws;
  float*          outbuf  = (float*)(ws + 67108864);
  unsigned short* vecb    = (unsigned short*)(ws + 134086656);
  unsigned short* wb      = (unsigned short*)(ws + 201129984);
  int*            fsrcG   = (int*)d_out + (size_t)512 * NC;   // batch-0 internal rows

  embed_scatter<<<16448, 256, 0, stream>>>(lcid, cmask, emb, lw,
                                           leafbuf, vecb, wb);
  compose_leafgemm<<<NB + 1024, 1024, 0, stream>>>(
      cinfo, lcid, cmask, leafbuf, outbuf, fsrcG,
      (const short*)vecb, (const short*)wb, lbias, out);
  gather_rows<<<NB * NT / 4, 256, 0, stream>>>(fsrcG, leafbuf, outbuf, vecb);
  gemm_int<<<2048, 256, 0, stream>>>(
      (const short*)vecb, (const short*)wb, lbias, out);
}